// Round 5
// baseline (239.114 us; speedup 1.0000x reference)
//
#include <hip/hip_runtime.h>
#include <math.h>

#define NJ 22
#define NC 33
#define BLOCK 256
#define OUTW 195  // (22 body + 43 joint) * 3

__global__ __launch_bounds__(BLOCK) void fk_kernel(
    const float* __restrict__ coords,    // B x NC
    const float* __restrict__ scales,    // B x NJ x 3
    const float* __restrict__ gBpJp_r,   // NJ x 3 x 3
    const float* __restrict__ gBpJp_t,   // NJ x 3
    const float* __restrict__ gJcBc_r,   // NJ x 3 x 3
    const float* __restrict__ gBcJc_t,   // NJ x 3
    const float* __restrict__ gBBcen_t,  // NJ x 3
    const float* __restrict__ gG_r,      // 3 x 3
    const float* __restrict__ gG_t,      // 3
    const float* __restrict__ grot_a,    // NJ x 3
    const float* __restrict__ grot_b,
    const float* __restrict__ gtrans_a,
    const float* __restrict__ gtrans_b,
    const int* __restrict__ grot_idx,    // NJ x 3
    const int* __restrict__ gtrans_idx,
    float* __restrict__ out,             // B x 65 x 3
    int Btot)
{
  constexpr int PAR[NJ] = {-1,0,0,0,1,1,3,2,2,3,5,6,8,9,10,11,12,13,14,15,16,17};

  __shared__ alignas(16) float s_coords[BLOCK * NC];     // stride 33 -> conflict-free
  __shared__ alignas(16) float s_matA[NJ][12];           // BpJp_r (9 used)
  __shared__ alignas(16) float s_matC[NJ][12];           // JcBc_r
  __shared__ alignas(16) float s_vBpJp[NJ][4], s_vBcJc[NJ][4], s_vBBc[NJ][4];
  __shared__ alignas(16) float s_ra[NJ][4], s_rb[NJ][4], s_ta[NJ][4], s_tb[NJ][4];
  __shared__ alignas(16) int   s_ri[NJ][4], s_ti[NJ][4];
  __shared__ alignas(16) float s_Gr[12];
  __shared__ alignas(16) float s_Gt[4];

  const int tid = threadIdx.x;

  // ---- stage per-joint constants (uniform, tiny) ----
  if (tid < NJ*9) {
    int j = tid / 9, k = tid - j*9;
    s_matA[j][k] = gBpJp_r[tid];
    s_matC[j][k] = gJcBc_r[tid];
  }
  if (tid < NJ*3) {
    int j = tid / 3, k = tid - j*3;
    s_vBpJp[j][k] = gBpJp_t[tid];
    s_vBcJc[j][k] = gBcJc_t[tid];
    s_vBBc[j][k]  = gBBcen_t[tid];
    s_ra[j][k] = grot_a[tid];
    s_rb[j][k] = grot_b[tid];
    s_ta[j][k] = gtrans_a[tid];
    s_tb[j][k] = gtrans_b[tid];
    s_ri[j][k] = grot_idx[tid];
    s_ti[j][k] = gtrans_idx[tid];
  }
  if (tid < 9) s_Gr[tid] = gG_r[tid];
  if (tid < 3) s_Gt[tid] = gG_t[tid];

  // ---- stage this block's coords rows, coalesced float4 ----
  {
    const long long base = (long long)blockIdx.x * (BLOCK * NC);
    const long long lim  = (long long)Btot * NC;
    if (base + BLOCK*NC <= lim) {
      const float4* s4 = reinterpret_cast<const float4*>(coords + base);
      float4* d4 = reinterpret_cast<float4*>(s_coords);
      constexpr int NV4  = (BLOCK*NC)/4;      // 2112
      constexpr int FULL = NV4 / BLOCK;       // 8
      constexpr int REM  = NV4 - FULL*BLOCK;  // 64
#pragma unroll
      for (int i = 0; i < FULL; ++i) d4[i*BLOCK + tid] = s4[i*BLOCK + tid];
      if (tid < REM) d4[FULL*BLOCK + tid] = s4[FULL*BLOCK + tid];
    } else {
      for (int k = tid; k < BLOCK*NC; k += BLOCK)
        if (base + k < lim) s_coords[k] = coords[base + k];
    }
  }
  __syncthreads();

  const int b = blockIdx.x * BLOCK + tid;
  if (b >= Btot) return;

  const float* cr = &s_coords[tid * NC];
  float* o = out + (long long)b * OUTW;

  // ---- per-thread scales row: 264 B is 8B-aligned -> float2 loads, |.| once ----
  float sv[NJ * 3];
  {
    const float2* s2 = reinterpret_cast<const float2*>(scales + (long long)b * (NJ*3));
#pragma unroll
    for (int i = 0; i < (NJ*3)/2; ++i) {
      const float2 v = s2[i];
      sv[2*i]   = fabsf(v.x);
      sv[2*i+1] = fabsf(v.y);
    }
  }

  float R[NJ][9], T[NJ][3];

#pragma unroll
  for (int j = 0; j < NJ; ++j) {
    const int p = PAR[j];

    const float sc0 = sv[j*3+0];
    const float sc1 = sv[j*3+1];
    const float sc2 = sv[j*3+2];

    float Rp[9], tp0, tp1, tp2, sp0, sp1, sp2;
    if (p < 0) {
#pragma unroll
      for (int i = 0; i < 9; ++i) Rp[i] = s_Gr[i];
      tp0 = s_Gt[0]; tp1 = s_Gt[1]; tp2 = s_Gt[2];
      sp0 = sp1 = sp2 = 1.0f;
    } else {
#pragma unroll
      for (int i = 0; i < 9; ++i) Rp[i] = R[p][i];
      tp0 = T[p][0]; tp1 = T[p][1]; tp2 = T[p][2];
      sp0 = sv[p*3+0]; sp1 = sv[p*3+1]; sp2 = sv[p*3+2];
    }

    // A = X_BpJp_r[j]
    float A[9];
#pragma unroll
    for (int i = 0; i < 9; ++i) A[i] = s_matA[j][i];

    // R_GJp = Rp @ A
    float RJp[9];
#pragma unroll
    for (int r = 0; r < 3; ++r) {
#pragma unroll
      for (int c = 0; c < 3; ++c) {
        RJp[r*3+c] = fmaf(Rp[r*3+0], A[c],
                     fmaf(Rp[r*3+1], A[3+c], Rp[r*3+2]*A[6+c]));
      }
    }

    // t_GJp = tp + Rp @ (X_BpJp_t * scale_p)
    const float v0 = s_vBpJp[j][0]*sp0, v1 = s_vBpJp[j][1]*sp1, v2 = s_vBpJp[j][2]*sp2;
    const float tJp0 = tp0 + fmaf(Rp[0], v0, fmaf(Rp[1], v1, Rp[2]*v2));
    const float tJp1 = tp1 + fmaf(Rp[3], v0, fmaf(Rp[4], v1, Rp[5]*v2));
    const float tJp2 = tp2 + fmaf(Rp[6], v0, fmaf(Rp[7], v1, Rp[8]*v2));
    if (p >= 0) {
      float* jo = o + 66 + 3*(2*j - 1);
      jo[0] = tJp0; jo[1] = tJp1; jo[2] = tJp2;
    }

    // euler angles + local translation (coords gathered from LDS, uniform idx)
    const float e0 = fmaf(s_ra[j][0], cr[s_ri[j][0]], s_rb[j][0]);
    const float e1 = fmaf(s_ra[j][1], cr[s_ri[j][1]], s_rb[j][1]);
    const float e2 = fmaf(s_ra[j][2], cr[s_ri[j][2]], s_rb[j][2]);
    const float tl0 = fmaf(s_ta[j][0], cr[s_ti[j][0]], s_tb[j][0]) * sp0;
    const float tl1 = fmaf(s_ta[j][1], cr[s_ti[j][1]], s_tb[j][1]) * sp1;
    const float tl2 = fmaf(s_ta[j][2], cr[s_ti[j][2]], s_tb[j][2]) * sp2;

    float sx, cx, sy, cy, sz, cz;
    __sincosf(e0, &sx, &cx);
    __sincosf(e1, &sy, &cy);
    __sincosf(e2, &sz, &cz);

    // R_loc = Rx(e0) @ Ry(e1) @ Rz(e2), closed form
    float Rl[9];
    Rl[0] = cy*cz;  Rl[1] = -cy*sz;  Rl[2] = sy;
    Rl[3] = fmaf(sx*sy, cz,  cx*sz);
    Rl[4] = fmaf(-sx*sy, sz, cx*cz);
    Rl[5] = -sx*cy;
    Rl[6] = fmaf(-cx*sy, cz, sx*sz);
    Rl[7] = fmaf(cx*sy, sz,  sx*cz);
    Rl[8] = cx*cy;

    // R_GJc = R_GJp @ R_loc
    float RJc[9];
#pragma unroll
    for (int r = 0; r < 3; ++r) {
#pragma unroll
      for (int c = 0; c < 3; ++c) {
        RJc[r*3+c] = fmaf(RJp[r*3+0], Rl[c],
                     fmaf(RJp[r*3+1], Rl[3+c], RJp[r*3+2]*Rl[6+c]));
      }
    }

    // t_GJc = t_GJp + R_GJp @ (t_loc * scale_p)   (tl already has sp)
    const float tJc0 = tJp0 + fmaf(RJp[0], tl0, fmaf(RJp[1], tl1, RJp[2]*tl2));
    const float tJc1 = tJp1 + fmaf(RJp[3], tl0, fmaf(RJp[4], tl1, RJp[5]*tl2));
    const float tJc2 = tJp2 + fmaf(RJp[6], tl0, fmaf(RJp[7], tl1, RJp[8]*tl2));
    {
      const int q = (j == 0) ? 0 : 2*j;
      float* jo = o + 66 + 3*q;
      jo[0] = tJc0; jo[1] = tJc1; jo[2] = tJc2;
    }

    // C = X_JcBc_r[j];  R_GBc = R_GJc @ C
    float C[9];
#pragma unroll
    for (int i = 0; i < 9; ++i) C[i] = s_matC[j][i];
    float* Rj = R[j];
#pragma unroll
    for (int r = 0; r < 3; ++r) {
#pragma unroll
      for (int c = 0; c < 3; ++c) {
        Rj[r*3+c] = fmaf(RJc[r*3+0], C[c],
                    fmaf(RJc[r*3+1], C[3+c], RJc[r*3+2]*C[6+c]));
      }
    }

    // t_GBc = t_GJc - R_GBc @ (X_BcJc_t * scale_c)
    const float w0 = s_vBcJc[j][0]*sc0, w1 = s_vBcJc[j][1]*sc1, w2 = s_vBcJc[j][2]*sc2;
    T[j][0] = tJc0 - fmaf(Rj[0], w0, fmaf(Rj[1], w1, Rj[2]*w2));
    T[j][1] = tJc1 - fmaf(Rj[3], w0, fmaf(Rj[4], w1, Rj[5]*w2));
    T[j][2] = tJc2 - fmaf(Rj[6], w0, fmaf(Rj[7], w1, Rj[8]*w2));

    // body_pos = t_GBc + R_GBc @ (X_BBcen_t * scale_c)
    const float u0 = s_vBBc[j][0]*sc0, u1 = s_vBBc[j][1]*sc1, u2 = s_vBBc[j][2]*sc2;
    o[j*3+0] = T[j][0] + fmaf(Rj[0], u0, fmaf(Rj[1], u1, Rj[2]*u2));
    o[j*3+1] = T[j][1] + fmaf(Rj[3], u0, fmaf(Rj[4], u1, Rj[5]*u2));
    o[j*3+2] = T[j][2] + fmaf(Rj[6], u0, fmaf(Rj[7], u1, Rj[8]*u2));
  }
}

extern "C" void kernel_launch(void* const* d_in, const int* in_sizes, int n_in,
                              void* d_out, int out_size, void* d_ws, size_t ws_size,
                              hipStream_t stream) {
  const float* coords   = (const float*)d_in[0];
  const float* scales   = (const float*)d_in[1];
  const float* BpJp_r   = (const float*)d_in[2];
  const float* BpJp_t   = (const float*)d_in[3];
  const float* JcBc_r   = (const float*)d_in[4];
  const float* BcJc_t   = (const float*)d_in[5];
  const float* BBcen_t  = (const float*)d_in[6];
  const float* G_r      = (const float*)d_in[7];
  const float* G_t      = (const float*)d_in[8];
  const float* rot_a    = (const float*)d_in[9];
  const float* rot_b    = (const float*)d_in[10];
  const float* trans_a  = (const float*)d_in[11];
  const float* trans_b  = (const float*)d_in[12];
  const int*   rot_idx  = (const int*)d_in[13];
  const int*   trans_idx= (const int*)d_in[14];
  float* out = (float*)d_out;

  const int Btot = in_sizes[0] / NC;
  const int grid = (Btot + BLOCK - 1) / BLOCK;

  fk_kernel<<<grid, BLOCK, 0, stream>>>(
      coords, scales, BpJp_r, BpJp_t, JcBc_r, BcJc_t, BBcen_t, G_r, G_t,
      rot_a, rot_b, trans_a, trans_b, rot_idx, trans_idx, out, Btot);
}

// Round 8
// 234.677 us; speedup vs baseline: 1.0189x; 1.0189x over previous
//
#include <hip/hip_runtime.h>
#include <math.h>

#define NJ 22
#define NC 33
#define BLOCK 64      // one wave per block
#define OUTW 195      // (22 body + 43 joint) * 3
#define SBW 55        // max 54 slots per phase; odd stride -> conflict-free

// One joint of the FK chain. MUST be called with compile-time-foldable j
// (from a #pragma unroll loop) so PAR[j] / R[p] stay statically indexed.
__device__ __forceinline__ void fk_joint(
    int j, int BODY0, int JNT0, int NB,
    const float* __restrict__ crow, const float* sv,
    float (&R)[NJ][9], float (&T)[NJ][3],
    float (*SB)[SBW], int tid,
    const float* s_matA, const float* s_matC,
    const float* s_vBpJp, const float* s_vBcJc, const float* s_vBBc,
    const float* s_ra, const float* s_rb, const float* s_ta, const float* s_tb,
    const int* s_ri, const int* s_ti,
    const float* s_Gr, const float* s_Gt)
{
  constexpr int PAR[NJ] = {-1,0,0,0,1,1,3,2,2,3,5,6,8,9,10,11,12,13,14,15,16,17};
  const int p = PAR[j];

  const float sc0 = sv[j*3+0], sc1 = sv[j*3+1], sc2 = sv[j*3+2];

  float Rp[9], tp0, tp1, tp2, sp0, sp1, sp2;
  if (p < 0) {
#pragma unroll
    for (int i = 0; i < 9; ++i) Rp[i] = s_Gr[i];
    tp0 = s_Gt[0]; tp1 = s_Gt[1]; tp2 = s_Gt[2];
    sp0 = sp1 = sp2 = 1.0f;
  } else {
#pragma unroll
    for (int i = 0; i < 9; ++i) Rp[i] = R[p][i];
    tp0 = T[p][0]; tp1 = T[p][1]; tp2 = T[p][2];
    sp0 = sv[p*3+0]; sp1 = sv[p*3+1]; sp2 = sv[p*3+2];
  }

  // A = X_BpJp_r[j];  R_GJp = Rp @ A
  float A[9];
#pragma unroll
  for (int i = 0; i < 9; ++i) A[i] = s_matA[j*9+i];
  float RJp[9];
#pragma unroll
  for (int r = 0; r < 3; ++r)
#pragma unroll
    for (int c = 0; c < 3; ++c)
      RJp[r*3+c] = fmaf(Rp[r*3+0], A[c],
                   fmaf(Rp[r*3+1], A[3+c], Rp[r*3+2]*A[6+c]));

  // t_GJp = tp + Rp @ (X_BpJp_t * scale_p)
  const float v0 = s_vBpJp[j*3+0]*sp0, v1 = s_vBpJp[j*3+1]*sp1, v2 = s_vBpJp[j*3+2]*sp2;
  const float tJp0 = tp0 + fmaf(Rp[0], v0, fmaf(Rp[1], v1, Rp[2]*v2));
  const float tJp1 = tp1 + fmaf(Rp[3], v0, fmaf(Rp[4], v1, Rp[5]*v2));
  const float tJp2 = tp2 + fmaf(Rp[6], v0, fmaf(Rp[7], v1, Rp[8]*v2));
  if (p >= 0) {
    const int s = (63 + 6*j) - JNT0 + NB;   // joint col 63+6j
    SB[tid][s+0] = tJp0; SB[tid][s+1] = tJp1; SB[tid][s+2] = tJp2;
  }

  // euler + local translation (coords gathered direct from global; idx uniform)
  const float e0 = fmaf(s_ra[j*3+0], crow[s_ri[j*3+0]], s_rb[j*3+0]);
  const float e1 = fmaf(s_ra[j*3+1], crow[s_ri[j*3+1]], s_rb[j*3+1]);
  const float e2 = fmaf(s_ra[j*3+2], crow[s_ri[j*3+2]], s_rb[j*3+2]);
  const float tl0 = fmaf(s_ta[j*3+0], crow[s_ti[j*3+0]], s_tb[j*3+0]) * sp0;
  const float tl1 = fmaf(s_ta[j*3+1], crow[s_ti[j*3+1]], s_tb[j*3+1]) * sp1;
  const float tl2 = fmaf(s_ta[j*3+2], crow[s_ti[j*3+2]], s_tb[j*3+2]) * sp2;

  float sx, cx, sy, cy, sz, cz;
  __sincosf(e0, &sx, &cx);
  __sincosf(e1, &sy, &cy);
  __sincosf(e2, &sz, &cz);

  // R_loc = Rx(e0) @ Ry(e1) @ Rz(e2), closed form
  float Rl[9];
  Rl[0] = cy*cz;  Rl[1] = -cy*sz;  Rl[2] = sy;
  Rl[3] = fmaf(sx*sy, cz,  cx*sz);
  Rl[4] = fmaf(-sx*sy, sz, cx*cz);
  Rl[5] = -sx*cy;
  Rl[6] = fmaf(-cx*sy, cz, sx*sz);
  Rl[7] = fmaf(cx*sy, sz,  sx*cz);
  Rl[8] = cx*cy;

  // R_GJc = R_GJp @ R_loc
  float RJc[9];
#pragma unroll
  for (int r = 0; r < 3; ++r)
#pragma unroll
    for (int c = 0; c < 3; ++c)
      RJc[r*3+c] = fmaf(RJp[r*3+0], Rl[c],
                   fmaf(RJp[r*3+1], Rl[3+c], RJp[r*3+2]*Rl[6+c]));

  // t_GJc = t_GJp + R_GJp @ (t_loc * scale_p)   (tl already has sp)
  const float tJc0 = tJp0 + fmaf(RJp[0], tl0, fmaf(RJp[1], tl1, RJp[2]*tl2));
  const float tJc1 = tJp1 + fmaf(RJp[3], tl0, fmaf(RJp[4], tl1, RJp[5]*tl2));
  const float tJc2 = tJp2 + fmaf(RJp[6], tl0, fmaf(RJp[7], tl1, RJp[8]*tl2));
  {
    const int s = (66 + 6*j) - JNT0 + NB;   // joint col 66+6j
    SB[tid][s+0] = tJc0; SB[tid][s+1] = tJc1; SB[tid][s+2] = tJc2;
  }

  // C = X_JcBc_r[j];  R_GBc = R_GJc @ C
  float C[9];
#pragma unroll
  for (int i = 0; i < 9; ++i) C[i] = s_matC[j*9+i];
  float* Rj = R[j];
#pragma unroll
  for (int r = 0; r < 3; ++r)
#pragma unroll
    for (int c = 0; c < 3; ++c)
      Rj[r*3+c] = fmaf(RJc[r*3+0], C[c],
                  fmaf(RJc[r*3+1], C[3+c], RJc[r*3+2]*C[6+c]));

  // t_GBc = t_GJc - R_GBc @ (X_BcJc_t * scale_c)
  const float w0 = s_vBcJc[j*3+0]*sc0, w1 = s_vBcJc[j*3+1]*sc1, w2 = s_vBcJc[j*3+2]*sc2;
  T[j][0] = tJc0 - fmaf(Rj[0], w0, fmaf(Rj[1], w1, Rj[2]*w2));
  T[j][1] = tJc1 - fmaf(Rj[3], w0, fmaf(Rj[4], w1, Rj[5]*w2));
  T[j][2] = tJc2 - fmaf(Rj[6], w0, fmaf(Rj[7], w1, Rj[8]*w2));

  // body_pos = t_GBc + R_GBc @ (X_BBcen_t * scale_c); body col 3j
  const float u0 = s_vBBc[j*3+0]*sc0, u1 = s_vBBc[j*3+1]*sc1, u2 = s_vBBc[j*3+2]*sc2;
  {
    const int s = 3*j - BODY0;
    SB[tid][s+0] = T[j][0] + fmaf(Rj[0], u0, fmaf(Rj[1], u1, Rj[2]*u2));
    SB[tid][s+1] = T[j][1] + fmaf(Rj[3], u0, fmaf(Rj[4], u1, Rj[5]*u2));
    SB[tid][s+2] = T[j][2] + fmaf(Rj[6], u0, fmaf(Rj[7], u1, Rj[8]*u2));
  }
}

// Coalesced flush: lane idx owns output column col for all 64 rows.
__device__ __forceinline__ void fk_flush(
    int BODY0, int JNT0, int NB, int S,
    const float (*SB)[SBW], float* __restrict__ out,
    long long base_b, int Btot, int tid)
{
  if (tid < S) {
    const int col = (tid < NB) ? (BODY0 + tid) : (JNT0 + tid - NB);
    for (int r = 0; r < BLOCK; ++r) {
      const long long row = base_b + r;
      if (row < Btot) out[row * OUTW + col] = SB[r][tid];
    }
  }
}

__global__ __launch_bounds__(BLOCK) void fk_kernel(
    const float* __restrict__ coords,    // B x NC
    const float* __restrict__ scales,    // B x NJ x 3
    const float* __restrict__ gBpJp_r, const float* __restrict__ gBpJp_t,
    const float* __restrict__ gJcBc_r, const float* __restrict__ gBcJc_t,
    const float* __restrict__ gBBcen_t,
    const float* __restrict__ gG_r, const float* __restrict__ gG_t,
    const float* __restrict__ grot_a, const float* __restrict__ grot_b,
    const float* __restrict__ gtrans_a, const float* __restrict__ gtrans_b,
    const int* __restrict__ grot_idx, const int* __restrict__ gtrans_idx,
    float* __restrict__ out, int Btot)
{
  __shared__ float SB[BLOCK][SBW];                       // 14.1 KB
  __shared__ float s_matA[NJ*9], s_matC[NJ*9];
  __shared__ float s_vBpJp[NJ*3], s_vBcJc[NJ*3], s_vBBc[NJ*3];
  __shared__ float s_ra[NJ*3], s_rb[NJ*3], s_ta[NJ*3], s_tb[NJ*3];
  __shared__ int   s_ri[NJ*3], s_ti[NJ*3];
  __shared__ float s_Gr[9], s_Gt[3];

  const int tid = threadIdx.x;

  for (int k = tid; k < NJ*9; k += BLOCK) { s_matA[k] = gBpJp_r[k]; s_matC[k] = gJcBc_r[k]; }
  for (int k = tid; k < NJ*3; k += BLOCK) {
    s_vBpJp[k] = gBpJp_t[k];  s_vBcJc[k] = gBcJc_t[k];  s_vBBc[k] = gBBcen_t[k];
    s_ra[k] = grot_a[k];  s_rb[k] = grot_b[k];
    s_ta[k] = gtrans_a[k]; s_tb[k] = gtrans_b[k];
    s_ri[k] = grot_idx[k]; s_ti[k] = gtrans_idx[k];
  }
  if (tid < 9) s_Gr[tid] = gG_r[tid];
  if (tid < 3) s_Gt[tid] = gG_t[tid];
  __syncthreads();

  const long long base_b = (long long)blockIdx.x * BLOCK;
  const long long bb = base_b + tid;
  const int b = (int)(bb < Btot ? bb : (long long)(Btot - 1));  // clamp loads only
  const float* crow = coords + (long long)b * NC;

  // per-thread scales row (264 B, 8B-aligned) as float2, |.| once
  float sv[NJ*3];
  {
    const float2* s2 = reinterpret_cast<const float2*>(scales + (long long)b * (NJ*3));
#pragma unroll
    for (int i = 0; i < (NJ*3)/2; ++i) {
      const float2 v = s2[i];
      sv[2*i]   = fabsf(v.x);
      sv[2*i+1] = fabsf(v.y);
    }
  }

  float R[NJ][9], T[NJ][3];

  // Phase 0: j 0..4  -> body cols [0,15), joint cols [66,93); 42 slots
#pragma unroll
  for (int j = 0; j <= 4; ++j)
    fk_joint(j, 0, 66, 15, crow, sv, R, T, SB, tid, s_matA, s_matC,
             s_vBpJp, s_vBcJc, s_vBBc, s_ra, s_rb, s_ta, s_tb, s_ri, s_ti, s_Gr, s_Gt);
  __syncthreads();
  fk_flush(0, 66, 15, 42, SB, out, base_b, Btot, tid);
  __syncthreads();

  // Phase 1: j 5..10 -> body [15,33), joints [93,129); 54 slots
#pragma unroll
  for (int j = 5; j <= 10; ++j)
    fk_joint(j, 15, 93, 18, crow, sv, R, T, SB, tid, s_matA, s_matC,
             s_vBpJp, s_vBcJc, s_vBBc, s_ra, s_rb, s_ta, s_tb, s_ri, s_ti, s_Gr, s_Gt);
  __syncthreads();
  fk_flush(15, 93, 18, 54, SB, out, base_b, Btot, tid);
  __syncthreads();

  // Phase 2: j 11..16 -> body [33,51), joints [129,165); 54 slots
#pragma unroll
  for (int j = 11; j <= 16; ++j)
    fk_joint(j, 33, 129, 18, crow, sv, R, T, SB, tid, s_matA, s_matC,
             s_vBpJp, s_vBcJc, s_vBBc, s_ra, s_rb, s_ta, s_tb, s_ri, s_ti, s_Gr, s_Gt);
  __syncthreads();
  fk_flush(33, 129, 18, 54, SB, out, base_b, Btot, tid);
  __syncthreads();

  // Phase 3: j 17..21 -> body [51,66), joints [165,195); 45 slots
#pragma unroll
  for (int j = 17; j <= 21; ++j)
    fk_joint(j, 51, 165, 15, crow, sv, R, T, SB, tid, s_matA, s_matC,
             s_vBpJp, s_vBcJc, s_vBBc, s_ra, s_rb, s_ta, s_tb, s_ri, s_ti, s_Gr, s_Gt);
  __syncthreads();
  fk_flush(51, 165, 15, 45, SB, out, base_b, Btot, tid);
}

extern "C" void kernel_launch(void* const* d_in, const int* in_sizes, int n_in,
                              void* d_out, int out_size, void* d_ws, size_t ws_size,
                              hipStream_t stream) {
  const float* coords   = (const float*)d_in[0];
  const float* scales   = (const float*)d_in[1];
  const float* BpJp_r   = (const float*)d_in[2];
  const float* BpJp_t   = (const float*)d_in[3];
  const float* JcBc_r   = (const float*)d_in[4];
  const float* BcJc_t   = (const float*)d_in[5];
  const float* BBcen_t  = (const float*)d_in[6];
  const float* G_r      = (const float*)d_in[7];
  const float* G_t      = (const float*)d_in[8];
  const float* rot_a    = (const float*)d_in[9];
  const float* rot_b    = (const float*)d_in[10];
  const float* trans_a  = (const float*)d_in[11];
  const float* trans_b  = (const float*)d_in[12];
  const int*   rot_idx  = (const int*)d_in[13];
  const int*   trans_idx= (const int*)d_in[14];
  float* out = (float*)d_out;

  const int Btot = in_sizes[0] / NC;
  const int grid = (Btot + BLOCK - 1) / BLOCK;

  fk_kernel<<<grid, BLOCK, 0, stream>>>(
      coords, scales, BpJp_r, BpJp_t, JcBc_r, BcJc_t, BBcen_t, G_r, G_t,
      rot_a, rot_b, trans_a, trans_b, rot_idx, trans_idx, out, Btot);
}